// Round 8
// baseline (45.462 us; speedup 1.0000x reference)
//
#include <hip/hip_runtime.h>

#define FDIM 32
#define LOG2E 1.44269504088896340f

typedef _Float16 half8 __attribute__((ext_vector_type(8)));
typedef float    f32x4 __attribute__((ext_vector_type(4)));
typedef float    f32x2 __attribute__((ext_vector_type(2)));

// base-2 sigmoid: expects z' = z*log2e already scaled; sigma = 1/(1+2^-z')
__device__ __forceinline__ float fsig2(float z2) {
    return __builtin_amdgcn_rcpf(1.0f + __builtin_amdgcn_exp2f(-z2));
}
// true sigmoid (prep only)
__device__ __forceinline__ float fsig(float z) {
    return __builtin_amdgcn_rcpf(1.0f + __builtin_amdgcn_exp2f(-z * LOG2E));
}

// Row-permutation: MFMA A-row rho = 16m + 4h + r  ->  tree slot (slot = node+1,
// heap: root=1, children of q are 2q/2q+1; level d = slots 2^d..2^(d+1)-1).
// Lane (s,h)'s 64 accumulator values are exactly the nodes its walk needs:
//   m=0          -> path slots 1+4h+r   (h==3,r==3 -> dummy slot 0)
//   m=1          -> L4: 16+4h+r
//   m=2..3       -> L5: 32+8h+4(m-2)+r
//   m=4..7       -> L6: 64+16h+4(m-4)+r
//   m=8..15      -> L7: 128+32h+8*((m-8)>>1) + 4*((m-8)&1) + r
__device__ __forceinline__ int row_to_slot(int rho) {
    int m = rho >> 4, h = (rho >> 2) & 3, r = rho & 3;
    if (m == 0)      return (h == 3 && r == 3) ? 0 : 1 + 4 * h + r;
    if (m == 1)      return 16 + 4 * h + r;
    if (m <= 3)      return 32 + 8 * h + 2 * (2 * (m - 2) + (r >> 1)) + (r & 1);
    if (m <= 7)      return 64 + 16 * h + 4 * (m - 4) + r;
    return 128 + 32 * h + 8 * ((m - 8) >> 1) + 4 * ((m - 8) & 1) + r;
}

// Prep (4 blocks x 256 thr; 4 threads per row, 8 k's each):
// Wh[rho][32] = relu(fi)*log2e in f16, negc[rho] = -c*log2e,
// Dtab[y] = {cls[2y]-cls[2y+1], cls[2y+1]}.
__global__ void dtree_prep(const float* __restrict__ fi, const float* __restrict__ fs,
                           const float* __restrict__ cls,
                           _Float16* __restrict__ Wh, float* __restrict__ negc,
                           float* __restrict__ Dtab) {
    int t = blockIdx.x * 256 + threadIdx.x;   // 0..1023
    if (t < 128) {
        float c0 = cls[2 * t], c1 = cls[2 * t + 1];
        Dtab[2 * t]     = c0 - c1;
        Dtab[2 * t + 1] = c1;
    }
    int rho = t >> 2, q = t & 3;              // row, k-quad (k = 8q..8q+7)
    int slot = row_to_slot(rho);
    half8 wv;
    float s = 0.0f;
    if (slot == 0) {
#pragma unroll
        for (int k0 = 0; k0 < 8; ++k0) wv[k0] = (_Float16)0.0f;
    } else {
        int node = slot - 1;
#pragma unroll
        for (int k0 = 0; k0 < 8; ++k0) {
            int k = 8 * q + k0;
            float w = fi[(node << 5) + k];
            w = w > 0.0f ? w : 0.0f;
            wv[k0] = (_Float16)(w * LOG2E);
            s = fmaf(w, fsig(fs[(node << 5) + k]), s);
        }
    }
    *(half8*)(Wh + (rho << 5) + 8 * q) = wv;
    s += __shfl_xor(s, 1, 64);
    s += __shfl_xor(s, 2, 64);
    if (q == 0) negc[rho] = -s * LOG2E;
}

// Upward combine of one depth-4 subtree (16 leaves) from register g's.
// v(node) = g*v_left + (1-g)*v_right = fma(g, vl - vr, vr).
__device__ __forceinline__ float subtree_val(const float* __restrict__ dtbj,
        f32x4 g7a, f32x4 g7b, f32x4 g6, float gE0, float gE1, float gD) {
    f32x4 dA = *(const f32x4*)(dtbj + 0);    // leaf pairs t=0,1: {D0,D1,D0,D1}
    f32x4 dB = *(const f32x4*)(dtbj + 4);    // t=2,3
    f32x4 dC = *(const f32x4*)(dtbj + 8);    // t=4,5
    f32x4 dE = *(const f32x4*)(dtbj + 12);   // t=6,7
    float v70 = fmaf(g7a[0], dA[0], dA[1]);
    float v71 = fmaf(g7a[1], dA[2], dA[3]);
    float v72 = fmaf(g7a[2], dB[0], dB[1]);
    float v73 = fmaf(g7a[3], dB[2], dB[3]);
    float v74 = fmaf(g7b[0], dC[0], dC[1]);
    float v75 = fmaf(g7b[1], dC[2], dC[3]);
    float v76 = fmaf(g7b[2], dE[0], dE[1]);
    float v77 = fmaf(g7b[3], dE[2], dE[3]);
    float v60 = fmaf(g6[0], v70 - v71, v71);
    float v61 = fmaf(g6[1], v72 - v73, v73);
    float v62 = fmaf(g6[2], v74 - v75, v75);
    float v63 = fmaf(g6[3], v76 - v77, v77);
    float v50 = fmaf(gE0, v60 - v61, v61);
    float v51 = fmaf(gE1, v62 - v63, v63);
    return fmaf(gD, v50 - v51, v51);
}

// Fused: 4 independent waves/block, 16 samples/wave, no block-wide syncs.
// cin/Dtab read from global (L1 broadcast); LDS used only for the 5 KB path
// exchange -> target 8 waves/SIMD (VGPR <= 64).
__global__ __launch_bounds__(256, 8) void dtree_fused(
    const float* __restrict__ x, const _Float16* __restrict__ Wh,
    const float* __restrict__ negc, const float* __restrict__ Dtab,
    float* __restrict__ out)
{
    __shared__ __align__(16) float pbuf[4][16][20];   // path exchange, wave-private

    const int tid = threadIdx.x;
    const int w = tid >> 6;          // wave in block (0..3)
    const int l = tid & 63;
    const int s = l & 15;            // sample col
    const int h = l >> 4;            // 16-lane group
    const int n = blockIdx.x * 64 + w * 16 + s;

    // B fragment: x[n][8h..8h+7] as f16
    const float* xrow = x + (size_t)n * FDIM + 8 * h;
    f32x4 xv0 = *(const f32x4*)(xrow);
    f32x4 xv1 = *(const f32x4*)(xrow + 4);
    half8 bfrag;
    bfrag[0] = (_Float16)xv0[0]; bfrag[1] = (_Float16)xv0[1];
    bfrag[2] = (_Float16)xv0[2]; bfrag[3] = (_Float16)xv0[3];
    bfrag[4] = (_Float16)xv1[0]; bfrag[5] = (_Float16)xv1[1];
    bfrag[6] = (_Float16)xv1[2]; bfrag[7] = (_Float16)xv1[3];

#define GROW(m, dst) do { \
    half8 afrag_ = *(const half8*)(Wh + ((16 * (m) + s) << 5) + 8 * h); \
    f32x4 cin_ = *(const f32x4*)(negc + 16 * (m) + 4 * h); \
    f32x4 acc_ = __builtin_amdgcn_mfma_f32_16x16x32_f16(afrag_, bfrag, cin_, 0, 0, 0); \
    dst[0] = fsig2(acc_[0]); dst[1] = fsig2(acc_[1]); \
    dst[2] = fsig2(acc_[2]); dst[3] = fsig2(acc_[3]); \
} while (0)

    // Path row first; overlap its LDS round-trip with rows 1,2.
    f32x4 pv; GROW(0, pv);
    *(f32x4*)(&pbuf[w][s][4 * h]) = pv;

    f32x4 gL4;  GROW(1, gL4);    // L4 g's, all 4 subtrees
    f32x4 gL5a; GROW(2, gL5a);   // L5 g's, subtrees 0,1

    // Wave-private cross-lane exchange: wave-local wait + scheduler fence.
    asm volatile("s_waitcnt lgkmcnt(0)" ::: "memory");
    __builtin_amdgcn_sched_barrier(0);

    const float* pb = &pbuf[w][s][0];
    float g1   = pb[0];                 // slot 1 (root)
    float gP2  = pb[1 + (h >> 1)];      // level 1
    float gP3  = pb[3 + h];             // level 2
    float gP4a = pb[7 + 2 * h];         // level 3, slot 8+2h
    float gP4b = pb[8 + 2 * h];         // level 3, slot 9+2h

    float f0 = (h & 2) ? 1.0f - g1  : g1;
    float f1 = (h & 1) ? 1.0f - gP2 : gP2;
    float f01 = f0 * f1;

    const float* dtb = Dtab + 64 * h;   // global, L1-resident per-h lines
    float facc = 0.0f;

    { // subtree j=0: rows 4, 8, 9
        f32x4 g6, g7a, g7b;
        GROW(4, g6); GROW(8, g7a); GROW(9, g7b);
        float p4 = f01 * (gP3 * gP4a);
        facc = fmaf(p4, subtree_val(dtb + 0, g7a, g7b, g6, gL5a[0], gL5a[1], gL4[0]), facc);
    }
    { // subtree j=1: rows 5, 10, 11
        f32x4 g6, g7a, g7b;
        GROW(5, g6); GROW(10, g7a); GROW(11, g7b);
        float p4 = f01 * (gP3 * (1.0f - gP4a));
        facc = fmaf(p4, subtree_val(dtb + 16, g7a, g7b, g6, gL5a[2], gL5a[3], gL4[1]), facc);
    }
    f32x4 gL5b; GROW(3, gL5b);   // L5 g's, subtrees 2,3
    { // subtree j=2: rows 6, 12, 13
        f32x4 g6, g7a, g7b;
        GROW(6, g6); GROW(12, g7a); GROW(13, g7b);
        float p4 = f01 * ((1.0f - gP3) * gP4b);
        facc = fmaf(p4, subtree_val(dtb + 32, g7a, g7b, g6, gL5b[0], gL5b[1], gL4[2]), facc);
    }
    { // subtree j=3: rows 7, 14, 15
        f32x4 g6, g7a, g7b;
        GROW(7, g6); GROW(14, g7a); GROW(15, g7b);
        float p4 = f01 * ((1.0f - gP3) * (1.0f - gP4b));
        facc = fmaf(p4, subtree_val(dtb + 48, g7a, g7b, g6, gL5b[2], gL5b[3], gL4[3]), facc);
    }
#undef GROW

    // combine the 4 h-lanes of each sample
    facc += __shfl_xor(facc, 16, 64);
    facc += __shfl_xor(facc, 32, 64);
    if (h == 0) out[n] = facc;
}

extern "C" void kernel_launch(void* const* d_in, const int* in_sizes, int n_in,
                              void* d_out, int out_size, void* d_ws, size_t ws_size,
                              hipStream_t stream) {
    const float* x   = (const float*)d_in[0];
    const float* fi  = (const float*)d_in[1];
    const float* fs  = (const float*)d_in[2];
    const float* cls = (const float*)d_in[3];

    _Float16* Wh = (_Float16*)d_ws;                        // 256*32*2 = 16 KB
    float* negc  = (float*)((char*)d_ws + 16384);          // 1 KB
    float* Dtab  = negc + 256;                             // 1 KB

    int nsamp = in_sizes[0] / FDIM;                        // 262144
    float* out = (float*)d_out;

    hipLaunchKernelGGL(dtree_prep, dim3(4), dim3(256), 0, stream, fi, fs, cls, Wh, negc, Dtab);
    hipLaunchKernelGGL(dtree_fused, dim3(nsamp / 64), dim3(256), 0, stream,
                       x, Wh, negc, Dtab, out);
}

// Round 9
// 44.021 us; speedup vs baseline: 1.0327x; 1.0327x over previous
//
#include <hip/hip_runtime.h>

#define FDIM 32
#define LOG2E 1.44269504088896340f

typedef _Float16 half8 __attribute__((ext_vector_type(8)));
typedef float    f32x4 __attribute__((ext_vector_type(4)));
typedef float    f32x2 __attribute__((ext_vector_type(2)));

// base-2 sigmoid: expects z' = z*log2e already scaled; sigma = 1/(1+2^-z')
__device__ __forceinline__ float fsig2(float z2) {
    return __builtin_amdgcn_rcpf(1.0f + __builtin_amdgcn_exp2f(-z2));
}
// true sigmoid (prep only)
__device__ __forceinline__ float fsig(float z) {
    return __builtin_amdgcn_rcpf(1.0f + __builtin_amdgcn_exp2f(-z * LOG2E));
}

// Row-permutation: MFMA A-row rho = 16m + 4h + r  ->  tree slot (slot = node+1,
// heap: root=1, children of q are 2q/2q+1; level d = slots 2^d..2^(d+1)-1).
// Lane (s,h)'s 64 accumulator values are exactly the nodes its walk needs:
//   m=0          -> path slots 1+4h+r   (h==3,r==3 -> dummy slot 0)
//   m=1          -> L4: 16+4h+r
//   m=2..3       -> L5: 32+8h+4(m-2)+r
//   m=4..7       -> L6: 64+16h+4(m-4)+r
//   m=8..15      -> L7: 128+32h+8*((m-8)>>1) + 4*((m-8)&1) + r
__device__ __forceinline__ int row_to_slot(int rho) {
    int m = rho >> 4, h = (rho >> 2) & 3, r = rho & 3;
    if (m == 0)      return (h == 3 && r == 3) ? 0 : 1 + 4 * h + r;
    if (m == 1)      return 16 + 4 * h + r;
    if (m <= 3)      return 32 + 8 * h + 2 * (2 * (m - 2) + (r >> 1)) + (r & 1);
    if (m <= 7)      return 64 + 16 * h + 4 * (m - 4) + r;
    return 128 + 32 * h + 8 * ((m - 8) >> 1) + 4 * ((m - 8) & 1) + r;
}

// Prep (4 blocks x 256 thr; 4 threads per row, 8 k's each):
// Wh[rho][32] = relu(fi)*log2e in f16, negc[rho] = -c*log2e,
// Dtab[y] = {cls[2y]-cls[2y+1], cls[2y+1]}.
__global__ void dtree_prep(const float* __restrict__ fi, const float* __restrict__ fs,
                           const float* __restrict__ cls,
                           _Float16* __restrict__ Wh, float* __restrict__ negc,
                           float* __restrict__ Dtab) {
    int t = blockIdx.x * 256 + threadIdx.x;   // 0..1023
    if (t < 128) {
        float c0 = cls[2 * t], c1 = cls[2 * t + 1];
        Dtab[2 * t]     = c0 - c1;
        Dtab[2 * t + 1] = c1;
    }
    int rho = t >> 2, q = t & 3;              // row, k-quad (k = 8q..8q+7)
    int slot = row_to_slot(rho);
    half8 wv;
    float s = 0.0f;
    if (slot == 0) {
#pragma unroll
        for (int k0 = 0; k0 < 8; ++k0) wv[k0] = (_Float16)0.0f;
    } else {
        int node = slot - 1;
#pragma unroll
        for (int k0 = 0; k0 < 8; ++k0) {
            int k = 8 * q + k0;
            float w = fi[(node << 5) + k];
            w = w > 0.0f ? w : 0.0f;
            wv[k0] = (_Float16)(w * LOG2E);
            s = fmaf(w, fsig(fs[(node << 5) + k]), s);
        }
    }
    *(half8*)(Wh + (rho << 5) + 8 * q) = wv;
    s += __shfl_xor(s, 1, 64);
    s += __shfl_xor(s, 2, 64);
    if (q == 0) negc[rho] = -s * LOG2E;
}

// Upward combine of one depth-4 subtree (16 leaves) from register g's.
// v(node) = g*v_left + (1-g)*v_right = fma(g, vl - vr, vr).
__device__ __forceinline__ float subtree_val(const float* __restrict__ dtbj,
        f32x4 g7a, f32x4 g7b, f32x4 g6, float gE0, float gE1, float gD) {
    f32x4 dA = *(const f32x4*)(dtbj + 0);    // leaf pairs t=0,1: {D0,D1,D0,D1}
    f32x4 dB = *(const f32x4*)(dtbj + 4);    // t=2,3
    f32x4 dC = *(const f32x4*)(dtbj + 8);    // t=4,5
    f32x4 dE = *(const f32x4*)(dtbj + 12);   // t=6,7
    float v70 = fmaf(g7a[0], dA[0], dA[1]);
    float v71 = fmaf(g7a[1], dA[2], dA[3]);
    float v72 = fmaf(g7a[2], dB[0], dB[1]);
    float v73 = fmaf(g7a[3], dB[2], dB[3]);
    float v74 = fmaf(g7b[0], dC[0], dC[1]);
    float v75 = fmaf(g7b[1], dC[2], dC[3]);
    float v76 = fmaf(g7b[2], dE[0], dE[1]);
    float v77 = fmaf(g7b[3], dE[2], dE[3]);
    float v60 = fmaf(g6[0], v70 - v71, v71);
    float v61 = fmaf(g6[1], v72 - v73, v73);
    float v62 = fmaf(g6[2], v74 - v75, v75);
    float v63 = fmaf(g6[3], v76 - v77, v77);
    float v50 = fmaf(gE0, v60 - v61, v61);
    float v51 = fmaf(gE1, v62 - v63, v63);
    return fmaf(gD, v50 - v51, v51);
}

// Fused: 4 independent waves/block, 16 samples/wave, no block-wide syncs.
// cin/Dtab read from global (L1 broadcast); LDS used only for the 5 KB path
// exchange. 6 waves/SIMD (VGPR <= 85) -- 8 forces catastrophic spill (R8).
__global__ __launch_bounds__(256, 6) void dtree_fused(
    const float* __restrict__ x, const _Float16* __restrict__ Wh,
    const float* __restrict__ negc, const float* __restrict__ Dtab,
    float* __restrict__ out)
{
    __shared__ __align__(16) float pbuf[4][16][20];   // path exchange, wave-private

    const int tid = threadIdx.x;
    const int w = tid >> 6;          // wave in block (0..3)
    const int l = tid & 63;
    const int s = l & 15;            // sample col
    const int h = l >> 4;            // 16-lane group
    const int n = blockIdx.x * 64 + w * 16 + s;

    // B fragment: x[n][8h..8h+7] as f16
    const float* xrow = x + (size_t)n * FDIM + 8 * h;
    f32x4 xv0 = *(const f32x4*)(xrow);
    f32x4 xv1 = *(const f32x4*)(xrow + 4);
    half8 bfrag;
    bfrag[0] = (_Float16)xv0[0]; bfrag[1] = (_Float16)xv0[1];
    bfrag[2] = (_Float16)xv0[2]; bfrag[3] = (_Float16)xv0[3];
    bfrag[4] = (_Float16)xv1[0]; bfrag[5] = (_Float16)xv1[1];
    bfrag[6] = (_Float16)xv1[2]; bfrag[7] = (_Float16)xv1[3];

#define GROW(m, dst) do { \
    half8 afrag_ = *(const half8*)(Wh + ((16 * (m) + s) << 5) + 8 * h); \
    f32x4 cin_ = *(const f32x4*)(negc + 16 * (m) + 4 * h); \
    f32x4 acc_ = __builtin_amdgcn_mfma_f32_16x16x32_f16(afrag_, bfrag, cin_, 0, 0, 0); \
    dst[0] = fsig2(acc_[0]); dst[1] = fsig2(acc_[1]); \
    dst[2] = fsig2(acc_[2]); dst[3] = fsig2(acc_[3]); \
} while (0)

    // Path row first; overlap its LDS round-trip with rows 1,2.
    f32x4 pv; GROW(0, pv);
    *(f32x4*)(&pbuf[w][s][4 * h]) = pv;

    f32x4 gL4;  GROW(1, gL4);    // L4 g's, all 4 subtrees
    f32x4 gL5a; GROW(2, gL5a);   // L5 g's, subtrees 0,1

    // Wave-private cross-lane exchange: wave-local wait + scheduler fence.
    asm volatile("s_waitcnt lgkmcnt(0)" ::: "memory");
    __builtin_amdgcn_sched_barrier(0);

    const float* pb = &pbuf[w][s][0];
    float g1   = pb[0];                 // slot 1 (root)
    float gP2  = pb[1 + (h >> 1)];      // level 1
    float gP3  = pb[3 + h];             // level 2
    float gP4a = pb[7 + 2 * h];         // level 3, slot 8+2h
    float gP4b = pb[8 + 2 * h];         // level 3, slot 9+2h

    float f0 = (h & 2) ? 1.0f - g1  : g1;
    float f1 = (h & 1) ? 1.0f - gP2 : gP2;
    float f01 = f0 * f1;

    const float* dtb = Dtab + 64 * h;   // global, L1-resident per-h lines
    float facc = 0.0f;

    { // subtree j=0: rows 4, 8, 9
        f32x4 g6, g7a, g7b;
        GROW(4, g6); GROW(8, g7a); GROW(9, g7b);
        float p4 = f01 * (gP3 * gP4a);
        facc = fmaf(p4, subtree_val(dtb + 0, g7a, g7b, g6, gL5a[0], gL5a[1], gL4[0]), facc);
    }
    { // subtree j=1: rows 5, 10, 11
        f32x4 g6, g7a, g7b;
        GROW(5, g6); GROW(10, g7a); GROW(11, g7b);
        float p4 = f01 * (gP3 * (1.0f - gP4a));
        facc = fmaf(p4, subtree_val(dtb + 16, g7a, g7b, g6, gL5a[2], gL5a[3], gL4[1]), facc);
    }
    f32x4 gL5b; GROW(3, gL5b);   // L5 g's, subtrees 2,3
    { // subtree j=2: rows 6, 12, 13
        f32x4 g6, g7a, g7b;
        GROW(6, g6); GROW(12, g7a); GROW(13, g7b);
        float p4 = f01 * ((1.0f - gP3) * gP4b);
        facc = fmaf(p4, subtree_val(dtb + 32, g7a, g7b, g6, gL5b[0], gL5b[1], gL4[2]), facc);
    }
    { // subtree j=3: rows 7, 14, 15
        f32x4 g6, g7a, g7b;
        GROW(7, g6); GROW(14, g7a); GROW(15, g7b);
        float p4 = f01 * ((1.0f - gP3) * (1.0f - gP4b));
        facc = fmaf(p4, subtree_val(dtb + 48, g7a, g7b, g6, gL5b[2], gL5b[3], gL4[3]), facc);
    }
#undef GROW

    // combine the 4 h-lanes of each sample
    facc += __shfl_xor(facc, 16, 64);
    facc += __shfl_xor(facc, 32, 64);
    if (h == 0) out[n] = facc;
}

extern "C" void kernel_launch(void* const* d_in, const int* in_sizes, int n_in,
                              void* d_out, int out_size, void* d_ws, size_t ws_size,
                              hipStream_t stream) {
    const float* x   = (const float*)d_in[0];
    const float* fi  = (const float*)d_in[1];
    const float* fs  = (const float*)d_in[2];
    const float* cls = (const float*)d_in[3];

    _Float16* Wh = (_Float16*)d_ws;                        // 256*32*2 = 16 KB
    float* negc  = (float*)((char*)d_ws + 16384);          // 1 KB
    float* Dtab  = negc + 256;                             // 1 KB

    int nsamp = in_sizes[0] / FDIM;                        // 262144
    float* out = (float*)d_out;

    hipLaunchKernelGGL(dtree_prep, dim3(4), dim3(256), 0, stream, fi, fs, cls, Wh, negc, Dtab);
    hipLaunchKernelGGL(dtree_fused, dim3(nsamp / 64), dim3(256), 0, stream,
                       x, Wh, negc, Dtab, out);
}

// Round 10
// 27.067 us; speedup vs baseline: 1.6796x; 1.6264x over previous
//
#include <hip/hip_runtime.h>

#define FDIM 32
#define LOG2E 1.44269504088896340f

typedef _Float16 half8  __attribute__((ext_vector_type(8)));
typedef float    f32x4  __attribute__((ext_vector_type(4)));
typedef float    f32x16 __attribute__((ext_vector_type(16)));

// base-2 sigmoid: z' = z*log2e pre-scaled; sigma = 1/(1+2^-z')
__device__ __forceinline__ float fsig2(float z2) {
    return __builtin_amdgcn_rcpf(1.0f + __builtin_amdgcn_exp2f(-z2));
}
// true sigmoid (prep only)
__device__ __forceinline__ float fsig(float z) {
    return __builtin_amdgcn_rcpf(1.0f + __builtin_amdgcn_exp2f(-z * LOG2E));
}

// 32x32 MFMA C-layout: col = lane&31 (sample), row32 = (r&3)+8*(r>>2)+4*hb,
// hb = lane>>5, r = C-reg 0..15. Global A-row rho = 32*b + row32 (block b of 8).
// Row permutation: lane (sample, hb), block b, reg r  ->  tree slot so that each
// lane's 16 regs = one complete depth-4 subtree J = 8*hb+b (15 nodes) + 1 path node.
//   r 0..7   -> L7: slot 128+8J+r   (leaf pair t=r)
//   r 8..11  -> L6: slot 64+4J+(r-8)
//   r 12..13 -> L5: slot 32+2J+(r-12)
//   r 14     -> L4: slot 16+J
//   r 15     -> path node: hb=0: {1,2,4,5,8,9,10,11}[b]; hb=1: {1,3,6,7,12,13,14,15}[b]
__device__ __forceinline__ int slot_of(int b, int hb, int r) {
    int J = 8 * hb + b;
    if (r < 8)   return 128 + 8 * J + r;
    if (r < 12)  return 64 + 4 * J + (r - 8);
    if (r < 14)  return 32 + 2 * J + (r - 12);
    if (r == 14) return 16 + J;
    if (b == 0)  return 1;                    // root (duplicated for both hb)
    if (b == 1)  return 2 + hb;
    if (b < 4)   return 4 + 2 * hb + (b - 2);
    return 8 + 4 * hb + (b - 4);
}

// Prep (4 blocks x 256 thr; 4 threads per row, 8 k's each):
// Wh[rho][32] = relu(fi[slot-1])*log2e f16 (permuted), negc[b*32+hb*16+r] =
// -c*log2e, Dtab[16J+2t] = {cls0-cls1, cls1} for leaf pair t of subtree J.
__global__ void dtree_prep(const float* __restrict__ fi, const float* __restrict__ fs,
                           const float* __restrict__ cls,
                           _Float16* __restrict__ Wh, float* __restrict__ negc,
                           float* __restrict__ Dtab) {
    int t = blockIdx.x * 256 + threadIdx.x;   // 0..1023
    if (t < 128) {
        float c0 = cls[2 * t], c1 = cls[2 * t + 1];
        Dtab[2 * t]     = c0 - c1;
        Dtab[2 * t + 1] = c1;
    }
    int rho = t >> 2, q = t & 3;              // permuted row, k-quad
    int b = rho >> 5, row32 = rho & 31;
    int hb = (row32 >> 2) & 1;
    int r = (row32 & 3) + 4 * (row32 >> 3);
    int node = slot_of(b, hb, r) - 1;
    half8 wv;
    float s = 0.0f;
#pragma unroll
    for (int k0 = 0; k0 < 8; ++k0) {
        int k = 8 * q + k0;
        float w = fi[(node << 5) + k];
        w = w > 0.0f ? w : 0.0f;
        wv[k0] = (_Float16)(w * LOG2E);
        s = fmaf(w, fsig(fs[(node << 5) + k]), s);
    }
    *(half8*)(Wh + (rho << 5) + 8 * q) = wv;
    s += __shfl_xor(s, 1, 64);
    s += __shfl_xor(s, 2, 64);
    if (q == 0) negc[b * 32 + hb * 16 + r] = -s * LOG2E;
}

// Fused: 4 waves/block, 32 samples/wave via 32x32x16 MFMA (2 per K=32 block).
// Each lane owns 8 complete subtrees + its own 8 path g's -> NO cross-lane
// exchange until the final shfl_xor(32). cin/Dtab broadcast from LDS.
__global__ __launch_bounds__(256, 6) void dtree_fused(
    const float* __restrict__ x, const _Float16* __restrict__ Wh,
    const float* __restrict__ negc, const float* __restrict__ Dtab,
    float* __restrict__ out)
{
    __shared__ __align__(64) float sNegc[256];   // 1 KB
    __shared__ __align__(64) float sDtab[256];   // 1 KB

    const int tid = threadIdx.x;
    const int w = tid >> 6;          // wave in block (0..3)
    const int l = tid & 63;
    const int s32 = l & 31;          // sample col
    const int hb = l >> 5;           // half-wave group
    const int n = blockIdx.x * 128 + w * 32 + s32;

    if (tid < 64)        ((f32x4*)sNegc)[tid]      = ((const f32x4*)negc)[tid];
    else if (tid < 128)  ((f32x4*)sDtab)[tid - 64] = ((const f32x4*)Dtab)[tid - 64];
    __syncthreads();

    // B fragments: frag0 = x[n][8hb..8hb+7] (k 0..15), frag1 = x[n][16+8hb..] (k 16..31)
    const float* xrow = x + (size_t)n * FDIM;
    f32x4 xa = *(const f32x4*)(xrow + 8 * hb);
    f32x4 xb = *(const f32x4*)(xrow + 8 * hb + 4);
    f32x4 xc = *(const f32x4*)(xrow + 16 + 8 * hb);
    f32x4 xd = *(const f32x4*)(xrow + 16 + 8 * hb + 4);
    half8 bf0, bf1;
    bf0[0] = (_Float16)xa[0]; bf0[1] = (_Float16)xa[1];
    bf0[2] = (_Float16)xa[2]; bf0[3] = (_Float16)xa[3];
    bf0[4] = (_Float16)xb[0]; bf0[5] = (_Float16)xb[1];
    bf0[6] = (_Float16)xb[2]; bf0[7] = (_Float16)xb[3];
    bf1[0] = (_Float16)xc[0]; bf1[1] = (_Float16)xc[1];
    bf1[2] = (_Float16)xc[2]; bf1[3] = (_Float16)xc[3];
    bf1[4] = (_Float16)xd[0]; bf1[5] = (_Float16)xd[1];
    bf1[6] = (_Float16)xd[2]; bf1[7] = (_Float16)xd[3];

    // One block b: 2 MFMAs (K=32) -> 16 g -> upward combine of subtree J=8hb+b.
#define BLOCKB(b, vout, pgout) do { \
    const _Float16* wr_ = Wh + ((32 * (b) + s32) << 5) + 8 * hb; \
    half8 a0_ = *(const half8*)(wr_); \
    half8 a1_ = *(const half8*)(wr_ + 16); \
    f32x16 ci_ = *(const f32x16*)(sNegc + (b) * 32 + hb * 16); \
    f32x16 ac_ = __builtin_amdgcn_mfma_f32_32x32x16_f16(a0_, bf0, ci_, 0, 0, 0); \
    ac_ = __builtin_amdgcn_mfma_f32_32x32x16_f16(a1_, bf1, ac_, 0, 0, 0); \
    const float* dj_ = sDtab + (8 * hb + (b)) * 16; \
    f32x4 dA_ = *(const f32x4*)(dj_); \
    f32x4 dB_ = *(const f32x4*)(dj_ + 4); \
    f32x4 dC_ = *(const f32x4*)(dj_ + 8); \
    f32x4 dD_ = *(const f32x4*)(dj_ + 12); \
    float v70_ = fmaf(fsig2(ac_[0]), dA_[0], dA_[1]); \
    float v71_ = fmaf(fsig2(ac_[1]), dA_[2], dA_[3]); \
    float v72_ = fmaf(fsig2(ac_[2]), dB_[0], dB_[1]); \
    float v73_ = fmaf(fsig2(ac_[3]), dB_[2], dB_[3]); \
    float v74_ = fmaf(fsig2(ac_[4]), dC_[0], dC_[1]); \
    float v75_ = fmaf(fsig2(ac_[5]), dC_[2], dC_[3]); \
    float v76_ = fmaf(fsig2(ac_[6]), dD_[0], dD_[1]); \
    float v77_ = fmaf(fsig2(ac_[7]), dD_[2], dD_[3]); \
    float v60_ = fmaf(fsig2(ac_[8]),  v70_ - v71_, v71_); \
    float v61_ = fmaf(fsig2(ac_[9]),  v72_ - v73_, v73_); \
    float v62_ = fmaf(fsig2(ac_[10]), v74_ - v75_, v75_); \
    float v63_ = fmaf(fsig2(ac_[11]), v76_ - v77_, v77_); \
    float v50_ = fmaf(fsig2(ac_[12]), v60_ - v61_, v61_); \
    float v51_ = fmaf(fsig2(ac_[13]), v62_ - v63_, v63_); \
    vout = fmaf(fsig2(ac_[14]), v50_ - v51_, v51_); \
    pgout = fsig2(ac_[15]); \
} while (0)

    float v0, v1, v2, v3, v4, v5, v6, v7;
    float pg0, pg1, pg2, pg3, pg4, pg5, pg6, pg7;
    BLOCKB(0, v0, pg0);
    BLOCKB(1, v1, pg1);
    BLOCKB(2, v2, pg2);
    BLOCKB(3, v3, pg3);
    BLOCKB(4, v4, pg4);
    BLOCKB(5, v5, pg5);
    BLOCKB(6, v6, pg6);
    BLOCKB(7, v7, pg7);
#undef BLOCKB

    // Path prefix products. pg0=root, pg1=slot 2+hb, pg2/3=slots 4/5+2hb,
    // pg4..7=slots 8..11 +4hb. Subtree jj=b: bits (jj>>2, jj>>1&1, jj&1).
    float f0   = hb ? (1.0f - pg0) : pg0;     // root factor (only hb-dependent one)
    float a01  = f0 * pg1;
    float a01n = f0 - a01;                    // f0*(1-pg1)
    float t0 = a01  * pg2, t1 = a01  - t0;
    float t2 = a01n * pg3, t3 = a01n - t2;
    float p0 = t0 * pg4, p1 = t0 - p0;
    float p2 = t1 * pg5, p3 = t1 - p2;
    float p4 = t2 * pg6, p5 = t2 - p4;
    float p6 = t3 * pg7, p7 = t3 - p6;

    float facc = p0 * v0;
    facc = fmaf(p1, v1, facc);
    facc = fmaf(p2, v2, facc);
    facc = fmaf(p3, v3, facc);
    facc = fmaf(p4, v4, facc);
    facc = fmaf(p5, v5, facc);
    facc = fmaf(p6, v6, facc);
    facc = fmaf(p7, v7, facc);

    // combine the two hb-halves of each sample
    facc += __shfl_xor(facc, 32, 64);
    if (l < 32) out[n] = facc;
}

extern "C" void kernel_launch(void* const* d_in, const int* in_sizes, int n_in,
                              void* d_out, int out_size, void* d_ws, size_t ws_size,
                              hipStream_t stream) {
    const float* x   = (const float*)d_in[0];
    const float* fi  = (const float*)d_in[1];
    const float* fs  = (const float*)d_in[2];
    const float* cls = (const float*)d_in[3];

    _Float16* Wh = (_Float16*)d_ws;                        // 256*32*2 = 16 KB
    float* negc  = (float*)((char*)d_ws + 16384);          // 1 KB
    float* Dtab  = negc + 256;                             // 1 KB

    int nsamp = in_sizes[0] / FDIM;                        // 262144
    float* out = (float*)d_out;

    hipLaunchKernelGGL(dtree_prep, dim3(4), dim3(256), 0, stream, fi, fs, cls, Wh, negc, Dtab);
    hipLaunchKernelGGL(dtree_fused, dim3(nsamp / 128), dim3(256), 0, stream,
                       x, Wh, negc, Dtab, out);
}